// Round 2
// baseline (1072.074 us; speedup 1.0000x reference)
//
#include <hip/hip_runtime.h>
#include <math.h>

#define BATCH  512
#define SEQ    2048
#define INPUT  64
#define HID    128
#define LB     8
#define NG     24              // 3*LB; slab layout [s][b][j][3] = (r,z,n) per j
#define T      16              // timesteps per chunk
#define NCHUNK (SEQ / T)       // 128
#define SLABF  (LB * NG)       // 192 floats per 8-batch timestep slab
#define CH_F   (T * SLABF)     // 3072 floats per chunk gate buffer
#define ROWS   (T * LB)        // 128 A-rows per chunk (r = bh*16 + sw)
#define AF4C   (ROWS * 16)     // 2048 float4 per A chunk (32 KB)
#define WPAD   17              // padded f4 stride for weight LDS (bank spread)

#define LOG2E  1.44269504088896340736f

typedef float v2f __attribute__((ext_vector_type(2)));

__device__ __forceinline__ v2f mk2(float a, float b) { v2f r; r.x = a; r.y = b; return r; }

#if __has_builtin(__builtin_amdgcn_exp2f)
#define EXP2F(x) __builtin_amdgcn_exp2f(x)
#else
#define EXP2F(x) __expf(0.69314718055994530942f * (x))
#endif

// ---------------------------------------------------------------------------
// Phase 0: fold fc_in + GRU input projection into one 24x64 matrix + bias,
// PRESCALED for exp2: rows r,z (g<16) by -log2e; rows n (g>=16) by +2*log2e.
// sigmoid(x) = rcp(1 + 2^(-log2e*x));  tanh(t) = 1 - 2*rcp(1 + 2^(2*log2e*t))
// ---------------------------------------------------------------------------
__global__ void precompute_kernel(const float* __restrict__ W_in,
                                  const float* __restrict__ b_in,
                                  const float* __restrict__ W_ih,
                                  const float* __restrict__ b_ih,
                                  const float* __restrict__ b_hh,
                                  float* __restrict__ Wc,   // [24][64] prescaled
                                  float* __restrict__ bc)   // [24]     prescaled
{
    int t = blockIdx.x * blockDim.x + threadIdx.x;
    if (t < NG * INPUT) {
        int g = t / INPUT, i = t % INPUT;
        float acc = 0.f;
        for (int h = 0; h < HID; ++h)
            acc += W_ih[g * HID + h] * W_in[h * INPUT + i];
        float sc = (g < 2 * LB) ? -LOG2E : 2.0f * LOG2E;
        Wc[t] = acc * sc;
    } else if (t < NG * INPUT + NG) {
        int g = t - NG * INPUT;
        float acc = b_ih[g];
        if (g < 2 * LB) acc += b_hh[g];
        for (int h = 0; h < HID; ++h)
            acc += W_ih[g * HID + h] * b_in[h];
        float sc = (g < 2 * LB) ? -LOG2E : 2.0f * LOG2E;
        bc[g] = acc * sc;
    }
}

// ---------------------------------------------------------------------------
// Fused kernel: 64 blocks x 256 threads (4 waves -> 4 SIMDs/CU).
//   waves 0-2 (producers): reg-staged A (11 global_load_dwordx4 issued at
//     round start, ds_write'd with XOR-swizzle after compute — no LDS-DMA,
//     so ds_reads never drain vmcnt). Weights in padded LDS (re-read per
//     chunk: 32 f4 reads), NOT registers — round-1's 128-VGPR weight array
//     spilled to scratch (VGPR_Count=132) and L2-latency reloads dominated.
//   wave 3 (consumer): validated DPP recurrence, exp2-prescaled gates.
// One __syncthreads per chunk; 129 barriers on every wave.
// ---------------------------------------------------------------------------
#define ROR2(v)  __int_as_float(__builtin_amdgcn_update_dpp(0, __float_as_int(v), 0x122, 0xF, 0xF, false))
#define ROR4(v)  __int_as_float(__builtin_amdgcn_update_dpp(0, __float_as_int(v), 0x124, 0xF, 0xF, false))
#define ROR8(v)  __int_as_float(__builtin_amdgcn_update_dpp(0, __float_as_int(v), 0x128, 0xF, 0xF, false))

#define GATHER8(sl, x) do {      \
    sl[0] = (x);                 \
    sl[1] = ROR2(sl[0]);         \
    sl[2] = ROR4(sl[0]);         \
    sl[3] = ROR4(sl[1]);         \
    sl[4] = ROR8(sl[0]);         \
    sl[5] = ROR8(sl[1]);         \
    sl[6] = ROR8(sl[2]);         \
    sl[7] = ROR8(sl[3]);         \
} while (0)

__global__ __launch_bounds__(256, 1) void fused_kernel(
    const float* __restrict__ A,     // [B][S][64]
    const float* __restrict__ Wc,    // [24][64] prescaled
    const float* __restrict__ bc,    // [24]     prescaled
    const float* __restrict__ W_hh,  // [24][8]  raw
    const float* __restrict__ b_hh,  // [24]     raw
    float* __restrict__ out)         // [B][8]
{
    __shared__ float4 abuf[2][AF4C];     // 64 KB: A chunk double buffer
    __shared__ float  sbuf[2][CH_F];     // 24 KB: gate slab double buffer
    __shared__ float4 wlds[NG * WPAD];   // 6.5 KB: padded prescaled weights

    const int tid = threadIdx.x;
    const int wv  = tid >> 6;
    const int l   = tid & 63;
    const int b0  = blockIdx.x * 8;

    // cooperative weight staging (visible after B0)
    {
        const float4* Wc4 = (const float4*)Wc;
        for (int idx = tid; idx < NG * 16; idx += 256)
            wlds[(idx >> 4) * WPAD + (idx & 15)] = Wc4[idx];
    }

    if (wv < 3) {
        // ---------------- producers (3 waves, 192 lanes) ----------------
        const int pg = wv * 64 + l;        // 0..191
        const int gp = pg % 12;            // gate pair
        const int rg = pg / 12;            // row group, 0..15 (8 rows each)
        const int g0 = gp * 2, g1 = g0 + 1;
        const int j0 = g0 & 7, t0 = g0 >> 3;
        const int j1 = g1 & 7, t1 = g1 >> 3;
        const int xk = rg & 7;             // swizzle key for this lane's rows
        const float bc0 = bc[g0], bc1 = bc[g1];

        // per-lane load slots: kk = k*3+wv (<32), q = kk*64+l
        int goff[11], loff[11];
#pragma unroll
        for (int k = 0; k < 11; ++k) {
            int kk = k * 3 + wv;
            if (kk < 32) {
                int q = kk * 64 + l;       // f4 index 0..2047
                int r = q >> 4;            // row = bh*16 + sw
                int i = q & 15;
                goff[k] = ((r >> 4) * SEQ + (r & 15)) * INPUT + i * 4;   // floats
                loff[k] = r * 16 + (i ^ ((r >> 3) & 7));                 // f4, swizzled
            } else { goff[k] = 0; loff[k] = 0; }
        }

        const float* gbase = A + (size_t)b0 * SEQ * INPUT;
        float4 rq[11];

        auto stage_load = [&]() {          // issue loads for next staged chunk
#pragma unroll
            for (int k = 0; k < 11; ++k)
                if (k * 3 + wv < 32) rq[k] = *(const float4*)(gbase + goff[k]);
            gbase += T * INPUT;            // advance one chunk (16 timesteps)
        };
        auto stage_write = [&](int h) {    // reg -> LDS (waits rq via reg use)
            float4* ab = &abuf[h][0];
#pragma unroll
            for (int k = 0; k < 11; ++k)
                if (k * 3 + wv < 32) ab[loff[k]] = rq[k];
        };
        auto compute_slab = [&](int h) {   // abuf[h] -> sbuf[h]
            const float4* ab = &abuf[h][0];
            float* sl = &sbuf[h][0];
            v2f acc0[8], acc1[8];
#pragma unroll
            for (int rit = 0; rit < 8; ++rit) {
                acc0[rit] = mk2(bc0, 0.f);
                acc1[rit] = mk2(bc1, 0.f);
            }
#pragma unroll
            for (int i = 0; i < 16; ++i) {
                float4 w0 = wlds[g0 * WPAD + i];
                float4 w1 = wlds[g1 * WPAD + i];
                v2f w0l = mk2(w0.x, w0.y), w0h = mk2(w0.z, w0.w);
                v2f w1l = mk2(w1.x, w1.y), w1h = mk2(w1.z, w1.w);
#pragma unroll
                for (int rit = 0; rit < 8; ++rit) {
                    float4 a4 = ab[(rg * 8 + rit) * 16 + (i ^ xk)];
                    v2f alo = mk2(a4.x, a4.y), ahi = mk2(a4.z, a4.w);
                    acc0[rit] += alo * w0l + ahi * w0h;
                    acc1[rit] += alo * w1l + ahi * w1h;
                }
            }
#pragma unroll
            for (int rit = 0; rit < 8; ++rit) {
                int r = rg * 8 + rit;
                float* sp = sl + (r & 15) * SLABF + (r >> 4) * (LB * 3);
                sp[j0 * 3 + t0] = acc0[rit].x + acc0[rit].y;
                sp[j1 * 3 + t1] = acc1[rit].x + acc1[rit].y;
            }
        };

        // prologue
        stage_load();                      // chunk 0
        stage_write(0);
        __syncthreads();                   // B0: abuf[0] + weights ready
        stage_load();                      // chunk 1
        compute_slab(0);                   // abuf[0] -> sbuf[0]
        stage_write(1);
        __syncthreads();                   // B1: sbuf[0] + abuf[1] ready

        for (int p = 0; p < NCHUNK; ++p) {
            if (p + 2 < NCHUNK) stage_load();            // chunk p+2 -> regs
            if (p + 1 < NCHUNK) compute_slab((p + 1) & 1);
            if (p + 2 < NCHUNK) stage_write(p & 1);      // abuf[(p+2)&1]
            if (p + 1 < NCHUNK) __syncthreads();
        }
    } else {
        // ---------------- consumer (wave 3) ----------------
        const int row = l >> 4;
        const int j   = (l >> 1) & 7;
        const int g   = l & 1;
        const int bh  = row * 2 + g;
        const int b   = b0 + bh;
        const int cofs = (bh * LB + j) * 3;

        // slot -> hidden-index map, resolved at runtime through the DPP net
        float jdxv[8];
        GATHER8(jdxv, (float)j);
        float wrs[8], wzs[8], wns[8];
#pragma unroll
        for (int m = 0; m < 8; ++m) {
            int idx = (int)(jdxv[m] + 0.5f);
            wrs[m] = W_hh[(0 * LB + j) * LB + idx] * (-LOG2E);
            wzs[m] = W_hh[(1 * LB + j) * LB + idx] * (-LOG2E);
            wns[m] = W_hh[(2 * LB + j) * LB + idx] * (2.0f * LOG2E);
        }
        v2f wr2[4], wz2[4], wn2[4];
#pragma unroll
        for (int m = 0; m < 4; ++m) {
            wr2[m] = mk2(wrs[2 * m], wrs[2 * m + 1]);
            wz2[m] = mk2(wzs[2 * m], wzs[2 * m + 1]);
            wn2[m] = mk2(wns[2 * m], wns[2 * m + 1]);
        }
        const float bhn = b_hh[2 * LB + j] * (2.0f * LOG2E);

        float h = 0.f;
        __syncthreads();                   // B0
        __syncthreads();                   // B1: sbuf[0] ready

        for (int p = 0; p < NCHUNK; ++p) {
            const float* Lb = &sbuf[p & 1][cofs];

            // 2-deep rotating LDS->reg prefetch
            float cr = Lb[0],         cz = Lb[1],         cn = Lb[2];
            float nr = Lb[SLABF + 0], nz = Lb[SLABF + 1], nn = Lb[SLABF + 2];
#pragma unroll
            for (int d = 0; d < T; ++d) {
                float fr = 0.f, fz = 0.f, fn = 0.f;
                if (d + 2 < T) {
                    const float* q = Lb + (d + 2) * SLABF;
                    fr = q[0]; fz = q[1]; fn = q[2];
                }

                float hs[8];
                GATHER8(hs, h);
                v2f h0 = mk2(hs[0], hs[1]);
                v2f h1 = mk2(hs[2], hs[3]);
                v2f h2 = mk2(hs[4], hs[5]);
                v2f h3 = mk2(hs[6], hs[7]);

                v2f srv = h0 * wr2[0] + h1 * wr2[1] + (h2 * wr2[2] + h3 * wr2[3]);
                v2f szv = h0 * wz2[0] + h1 * wz2[1] + (h2 * wz2[2] + h3 * wz2[3]);
                v2f snv = h0 * wn2[0] + h1 * wn2[1] + (h2 * wn2[2] + h3 * wn2[3]);

                float dr = cr + (srv.x + srv.y);   // already -log2e scaled
                float dz = cz + (szv.x + szv.y);
                float dn = bhn + (snv.x + snv.y);  // already 2*log2e scaled

                float er = EXP2F(dr);
                float ez = EXP2F(dz);
                float rr = __builtin_amdgcn_rcpf(1.f + er);  // sigmoid(dr_orig)
                float zz = __builtin_amdgcn_rcpf(1.f + ez);

                float tt = fmaf(rr, dn, cn);       // = 2*log2e * t_orig
                float en = EXP2F(tt);              // = exp(2*t_orig)
                float nv = fmaf(-2.f, __builtin_amdgcn_rcpf(1.f + en), 1.f); // tanh

                h = fmaf(zz, h - nv, nv);

                cr = nr; cz = nz; cn = nn;
                nr = fr; nz = fz; nn = fn;
            }
            if (p + 1 < NCHUNK) __syncthreads();
        }

        out[b * LB + j] = h;
    }
}

// ---------------------------------------------------------------------------
extern "C" void kernel_launch(void* const* d_in, const int* in_sizes, int n_in,
                              void* d_out, int out_size, void* d_ws, size_t ws_size,
                              hipStream_t stream) {
    const float* A    = (const float*)d_in[0];  // (512, 2048, 64)
    const float* W_in = (const float*)d_in[1];  // (128, 64)
    const float* b_in = (const float*)d_in[2];  // (128,)
    const float* W_ih = (const float*)d_in[3];  // (24, 128)
    const float* W_hh = (const float*)d_in[4];  // (24, 8)
    const float* b_ih = (const float*)d_in[5];  // (24,)
    const float* b_hh = (const float*)d_in[6];  // (24,)
    float* out = (float*)d_out;                 // (512, 8)

    // workspace: Wc [24][64] | bc [24]   (gates tensor eliminated)
    float* Wc = (float*)d_ws;
    float* bc = Wc + NG * INPUT;

    precompute_kernel<<<7, 256, 0, stream>>>(W_in, b_in, W_ih, b_ih, b_hh, Wc, bc);
    fused_kernel<<<BATCH / 8, 256, 0, stream>>>(A, Wc, bc, W_hh, b_hh, out);
}

// Round 3
// 816.732 us; speedup vs baseline: 1.3126x; 1.3126x over previous
//
#include <hip/hip_runtime.h>
#include <math.h>

#define BATCH  512
#define SEQ    2048
#define INPUT  64
#define HID    128
#define LB     8
#define NG     24              // 3*LB gates; columns ordered r(0:8) z(8:16) n(16:24)
#define T      16              // timesteps per chunk
#define NCHUNK (SEQ / T)       // 128
#define BPB    2               // batches per block -> 256 blocks (all CUs)
#define RPC    (BPB * T)       // 32 gate-rows per chunk (row = bh*16 + sw)
#define RSTR   28              // sbuf row stride in floats (16B-aligned, bank-spread)

#define LOG2E  1.44269504088896340736f

typedef float v2f __attribute__((ext_vector_type(2)));
__device__ __forceinline__ v2f mk2(float a, float b) { v2f r; r.x = a; r.y = b; return r; }

#if __has_builtin(__builtin_amdgcn_exp2f)
#define EXP2F(x) __builtin_amdgcn_exp2f(x)
#else
#define EXP2F(x) __expf(0.69314718055994530942f * (x))
#endif

// ---------------------------------------------------------------------------
// Phase 0: fold fc_in + GRU input projection into one 24x64 matrix + bias,
// PRESCALED for exp2: rows r,z (g<16) by -log2e; rows n (g>=16) by +2*log2e.
// sigmoid(x) = rcp(1 + 2^(-log2e*x));  tanh(t) = 1 - 2*rcp(1 + 2^(2*log2e*t))
// ---------------------------------------------------------------------------
__global__ void precompute_kernel(const float* __restrict__ W_in,
                                  const float* __restrict__ b_in,
                                  const float* __restrict__ W_ih,
                                  const float* __restrict__ b_ih,
                                  const float* __restrict__ b_hh,
                                  float* __restrict__ Wc,   // [24][64] prescaled
                                  float* __restrict__ bc)   // [24]     prescaled
{
    int t = blockIdx.x * blockDim.x + threadIdx.x;
    if (t < NG * INPUT) {
        int g = t / INPUT, i = t % INPUT;
        float acc = 0.f;
        for (int h = 0; h < HID; ++h)
            acc += W_ih[g * HID + h] * W_in[h * INPUT + i];
        float sc = (g < 2 * LB) ? -LOG2E : 2.0f * LOG2E;
        Wc[t] = acc * sc;
    } else if (t < NG * INPUT + NG) {
        int g = t - NG * INPUT;
        float acc = b_ih[g];
        if (g < 2 * LB) acc += b_hh[g];
        for (int h = 0; h < HID; ++h)
            acc += W_ih[g * HID + h] * b_in[h];
        float sc = (g < 2 * LB) ? -LOG2E : 2.0f * LOG2E;
        bc[g] = acc * sc;
    }
}

// ---------------------------------------------------------------------------
// Fused kernel: 256 blocks x 128 threads (2 waves), 2 batches per block.
//   wave 0 (producer): lane = (row r = l>>1 of 32, half h = l&1). A half-row
//     (32 floats) lives in REGISTERS (8xfloat4, double-buffered, plain global
//     loads -> no LDS staging, no vmcnt at barriers for reg loads). Weights
//     broadcast-read from LDS (2 distinct addrs/instr -> conflict-free).
//     Halves combined with one quad_perm DPP add; h==0 writes 6 float4.
//   wave 1 (consumer): validated DPP recurrence, exp2-prescaled gates; bias
//     added at prefetch time (off the critical path). Lanes 32-63 duplicate
//     lanes 0-31 (valid reads, stores guarded by bh<BPB).
// Barrier count: 1 init + 128 rounds on both waves.
// ---------------------------------------------------------------------------
#define ROR2(v)  __int_as_float(__builtin_amdgcn_update_dpp(0, __float_as_int(v), 0x122, 0xF, 0xF, false))
#define ROR4(v)  __int_as_float(__builtin_amdgcn_update_dpp(0, __float_as_int(v), 0x124, 0xF, 0xF, false))
#define ROR8(v)  __int_as_float(__builtin_amdgcn_update_dpp(0, __float_as_int(v), 0x128, 0xF, 0xF, false))
#define SWAP1(v) __int_as_float(__builtin_amdgcn_update_dpp(0, __float_as_int(v), 0x0B1, 0xF, 0xF, false))

#define GATHER8(sl, x) do {      \
    sl[0] = (x);                 \
    sl[1] = ROR2(sl[0]);         \
    sl[2] = ROR4(sl[0]);         \
    sl[3] = ROR4(sl[1]);         \
    sl[4] = ROR8(sl[0]);         \
    sl[5] = ROR8(sl[1]);         \
    sl[6] = ROR8(sl[2]);         \
    sl[7] = ROR8(sl[3]);         \
} while (0)

__device__ __forceinline__ void prod_round(
    int c, int r, int h,
    const float* __restrict__ arow,   // this lane's half-row base (chunk 0)
    const float4* __restrict__ wl,    // wlds4 + h*8
    float* __restrict__ sbuf,
    float4 (&cur)[8], float4 (&nxt)[8])
{
    // issue next chunk's loads early: they stay in flight across barriers
    if (c + 1 < NCHUNK) {
        const float* src = arow + (size_t)(c + 1) * (T * INPUT);
#pragma unroll
        for (int i = 0; i < 8; ++i)
            nxt[i] = *(const float4*)(src + i * 4);
    }

    v2f acc[NG];
#pragma unroll
    for (int g = 0; g < NG; ++g) acc[g] = mk2(0.f, 0.f);
#pragma unroll
    for (int g = 0; g < NG; ++g) {
#pragma unroll
        for (int i = 0; i < 8; ++i) {
            float4 w = wl[g * 16 + i];      // broadcast (2 addrs per instr)
            float4 a = cur[i];
            acc[g] += mk2(a.x, a.y) * mk2(w.x, w.y)
                    + mk2(a.z, a.w) * mk2(w.z, w.w);
        }
    }

    float s[NG];
#pragma unroll
    for (int g = 0; g < NG; ++g) {
        float v = acc[g].x + acc[g].y;
        s[g] = v + SWAP1(v);                // combine the two half-row dots
    }

    if (h == 0) {
        float4* dst = (float4*)(sbuf + (c & 1) * (RPC * RSTR) + r * RSTR);
#pragma unroll
        for (int q = 0; q < 6; ++q)
            dst[q] = make_float4(s[4 * q], s[4 * q + 1], s[4 * q + 2], s[4 * q + 3]);
    }
    __syncthreads();
}

__global__ __launch_bounds__(128, 1) void fused_kernel(
    const float* __restrict__ A,     // [B][S][64]
    const float* __restrict__ Wc,    // [24][64] prescaled
    const float* __restrict__ bc,    // [24]     prescaled
    const float* __restrict__ W_hh,  // [24][8]  raw
    const float* __restrict__ b_hh,  // [24]     raw
    float* __restrict__ out)         // [B][8]
{
    __shared__ float  sbuf[2 * RPC * RSTR];   // 7168 B gate slab, double-buffered
    __shared__ float4 wlds4[NG * 16];         // 6144 B prescaled weights

    const int tid = threadIdx.x;
    const int wv  = tid >> 6;
    const int l   = tid & 63;
    const int b0  = blockIdx.x * BPB;

    // cooperative weight staging (visible after B_init)
    {
        const float4* Wc4 = (const float4*)Wc;
        for (int idx = tid; idx < NG * 16; idx += 128)
            wlds4[idx] = Wc4[idx];
    }

    if (wv == 0) {
        // ---------------- producer ----------------
        const int r = l >> 1;          // gate-row 0..31: bh = r>>4, sw = r&15
        const int h = l & 1;           // which half of the 64-float A row
        const float* arow = A + ((size_t)(b0 + (r >> 4)) * SEQ + (r & 15)) * INPUT
                              + h * 32;
        const float4* wl = wlds4 + h * 8;

        float4 a0[8], a1[8];
#pragma unroll
        for (int i = 0; i < 8; ++i)    // chunk 0 -> a0 (issued before B_init)
            a0[i] = *(const float4*)(arow + i * 4);

        __syncthreads();               // B_init: weights staged

        prod_round(0, r, h, arow, wl, sbuf, a0, a1);
        for (int p = 1; p < NCHUNK - 1; p += 2) {
            prod_round(p,     r, h, arow, wl, sbuf, a1, a0);
            prod_round(p + 1, r, h, arow, wl, sbuf, a0, a1);
        }
        prod_round(NCHUNK - 1, r, h, arow, wl, sbuf, a1, a0);
    } else {
        // ---------------- consumer ----------------
        const int row = l >> 4;
        const int j   = (l >> 1) & 7;
        const int g   = l & 1;
        const int bh  = row * 2 + g;          // 0..7
        const int bhc = bh & (BPB - 1);       // duplicate mapping for idle lanes

        // slot -> hidden-index map, resolved at runtime through the DPP net
        float jdxv[8];
        GATHER8(jdxv, (float)j);
        float wrs[8], wzs[8], wns[8];
#pragma unroll
        for (int m = 0; m < 8; ++m) {
            int idx = (int)(jdxv[m] + 0.5f);
            wrs[m] = W_hh[(0 * LB + j) * LB + idx] * (-LOG2E);
            wzs[m] = W_hh[(1 * LB + j) * LB + idx] * (-LOG2E);
            wns[m] = W_hh[(2 * LB + j) * LB + idx] * (2.0f * LOG2E);
        }
        v2f wr2[4], wz2[4], wn2[4];
#pragma unroll
        for (int m = 0; m < 4; ++m) {
            wr2[m] = mk2(wrs[2 * m], wrs[2 * m + 1]);
            wz2[m] = mk2(wzs[2 * m], wzs[2 * m + 1]);
            wn2[m] = mk2(wns[2 * m], wns[2 * m + 1]);
        }
        const float bxr = bc[j];              // prescaled input-side biases
        const float bxz = bc[8 + j];
        const float bxn = bc[16 + j];
        const float bhn = b_hh[2 * LB + j] * (2.0f * LOG2E);

        float hreg = 0.f;
        __syncthreads();                      // B_init
        __syncthreads();                      // producer round 0: sbuf[0] ready

        for (int p = 0; p < NCHUNK; ++p) {
            const float* Lb = sbuf + (p & 1) * (RPC * RSTR) + bhc * (T * RSTR) + j;

            // 2-deep rotating LDS->reg prefetch; bias folded in off-path
            float cr = Lb[0]  + bxr, cz = Lb[8]  + bxz, cn = Lb[16] + bxn;
            float nr = Lb[RSTR] + bxr, nz = Lb[RSTR + 8] + bxz, nn = Lb[RSTR + 16] + bxn;
#pragma unroll
            for (int d = 0; d < T; ++d) {
                float fr = 0.f, fz = 0.f, fn = 0.f;
                if (d + 2 < T) {
                    const float* q = Lb + (d + 2) * RSTR;
                    fr = q[0] + bxr; fz = q[8] + bxz; fn = q[16] + bxn;
                }

                float hs[8];
                GATHER8(hs, hreg);
                v2f h0 = mk2(hs[0], hs[1]);
                v2f h1 = mk2(hs[2], hs[3]);
                v2f h2 = mk2(hs[4], hs[5]);
                v2f h3 = mk2(hs[6], hs[7]);

                v2f srv = h0 * wr2[0] + h1 * wr2[1] + (h2 * wr2[2] + h3 * wr2[3]);
                v2f szv = h0 * wz2[0] + h1 * wz2[1] + (h2 * wz2[2] + h3 * wz2[3]);
                v2f snv = h0 * wn2[0] + h1 * wn2[1] + (h2 * wn2[2] + h3 * wn2[3]);

                float dr = cr + (srv.x + srv.y);   // already -log2e scaled
                float dz = cz + (szv.x + szv.y);
                float dn = bhn + (snv.x + snv.y);  // already 2*log2e scaled

                float er = EXP2F(dr);
                float ez = EXP2F(dz);
                float rr = __builtin_amdgcn_rcpf(1.f + er);  // sigmoid
                float zz = __builtin_amdgcn_rcpf(1.f + ez);

                float tt = fmaf(rr, dn, cn);       // = 2*log2e * t_orig
                float en = EXP2F(tt);              // = exp(2*t_orig)
                float nv = fmaf(-2.f, __builtin_amdgcn_rcpf(1.f + en), 1.f); // tanh

                hreg = fmaf(zz, hreg - nv, nv);

                cr = nr; cz = nz; cn = nn;
                nr = fr; nz = fz; nn = fn;
            }
            if (p + 1 < NCHUNK) __syncthreads();
        }

        if (bh < BPB)
            out[(b0 + bh) * LB + j] = hreg;
    }
}

// ---------------------------------------------------------------------------
extern "C" void kernel_launch(void* const* d_in, const int* in_sizes, int n_in,
                              void* d_out, int out_size, void* d_ws, size_t ws_size,
                              hipStream_t stream) {
    const float* A    = (const float*)d_in[0];  // (512, 2048, 64)
    const float* W_in = (const float*)d_in[1];  // (128, 64)
    const float* b_in = (const float*)d_in[2];  // (128,)
    const float* W_ih = (const float*)d_in[3];  // (24, 128)
    const float* W_hh = (const float*)d_in[4];  // (24, 8)
    const float* b_ih = (const float*)d_in[5];  // (24,)
    const float* b_hh = (const float*)d_in[6];  // (24,)
    float* out = (float*)d_out;                 // (512, 8)

    // workspace: Wc [24][64] | bc [24]
    float* Wc = (float*)d_ws;
    float* bc = Wc + NG * INPUT;

    precompute_kernel<<<7, 256, 0, stream>>>(W_in, b_in, W_ih, b_ih, b_hh, Wc, bc);
    fused_kernel<<<BATCH / BPB, 128, 0, stream>>>(A, Wc, bc, W_hh, b_hh, out);
}